// Round 1
// 491.709 us; speedup vs baseline: 1.2690x; 1.2690x over previous
//
#include <hip/hip_runtime.h>
#include <math.h>

#define B_ 4
#define N_ 4096
#define C_ 1024
#define H_ 16
#define D_ 64
#define M_ (B_*N_)      // 16384 rows
#define GK 1024         // GEMM K dim (both GEMMs)
#define NCH 8           // N-chunks for kv partial reduction
#define CHROWS (N_/NCH) // 512

typedef __attribute__((ext_vector_type(8))) _Float16 f16x8;
typedef __attribute__((ext_vector_type(4))) _Float16 f16x4;
typedef __attribute__((ext_vector_type(4))) float f32x4;

__device__ __forceinline__ float phi_f(float t) {
  return (t > 0.0f) ? (t + 1.0f) : __expf(t);
}

#define GLOAD(gp, lp) __builtin_amdgcn_global_load_lds( \
    (const __attribute__((address_space(1))) unsigned int*)(gp), \
    (__attribute__((address_space(3))) unsigned int*)(lp), 16, 0, 0)

#define BAR() __builtin_amdgcn_s_barrier()
#define WAITL0() asm volatile("s_waitcnt lgkmcnt(0)" ::: "memory")
#define WAITV6() asm volatile("s_waitcnt vmcnt(6)" ::: "memory")
#define WAITV0() asm volatile("s_waitcnt vmcnt(0)" ::: "memory")
#define PRIO1() __builtin_amdgcn_s_setprio(1)
#define PRIO0() __builtin_amdgcn_s_setprio(0)

__device__ __forceinline__ f32x4 mfma16h(f16x8 a, f16x8 b, f32x4 c) {
  return __builtin_amdgcn_mfma_f32_16x16x32_f16(a, b, c, 0, 0, 0);
}

// ---------------- mask dtype detection ----------------
__global__ __launch_bounds__(256) void mask_detect_k(const unsigned int* __restrict__ w,
                                                     int* __restrict__ flag) {
  __shared__ int notint, notflt;
  if (threadIdx.x == 0) { notint = 0; notflt = 0; }
  __syncthreads();
  int ni = 0, nf = 0;
  for (int i = threadIdx.x; i < 4096; i += 256) {
    unsigned int v = w[i];
    if (v > 1u) ni = 1;
    if (v != 0u && v != 0x3F800000u) nf = 1;
  }
  if (ni) atomicOr(&notint, 1);
  if (nf) atomicOr(&notflt, 1);
  __syncthreads();
  if (threadIdx.x == 0) *flag = (!notint) ? 0 : ((!notflt) ? 1 : 2);
}

__global__ __launch_bounds__(256) void mask_convert_k(const void* __restrict__ mask,
                                                      const int* __restrict__ flag,
                                                      float* __restrict__ valid) {
  int i = blockIdx.x * 256 + threadIdx.x;  // 16384 total
  int f = *flag;
  int m;
  if (f == 0)      m = ((const int*)mask)[i] != 0;
  else if (f == 1) m = ((const float*)mask)[i] != 0.0f;
  else             m = ((const unsigned char*)mask)[i] != 0;
  valid[i] = m ? 0.0f : 1.0f;  // True = PAD -> 0
}

// ---------------- fp32 -> fp16 single convert (x4) ----------------
__global__ __launch_bounds__(256) void conv_f16_k(const float* __restrict__ src,
                                                  _Float16* __restrict__ dst, int n4) {
  int i = blockIdx.x * 256 + threadIdx.x;
  if (i >= n4) return;
  float4 v = ((const float4*)src)[i];
  f16x4 h;
  h[0] = (_Float16)v.x; h[1] = (_Float16)v.y;
  h[2] = (_Float16)v.z; h[3] = (_Float16)v.w;
  ((f16x4*)dst)[i] = h;
}

// ---------------- fp32 -> fp16 hi/lo split (x4) ----------------
__global__ __launch_bounds__(256) void split_f16_k(const float* __restrict__ src,
                                                   _Float16* __restrict__ h,
                                                   _Float16* __restrict__ l, int n4) {
  int i = blockIdx.x * 256 + threadIdx.x;
  if (i >= n4) return;
  float4 v = ((const float4*)src)[i];
  f16x4 hv, lv;
  float vs[4] = {v.x, v.y, v.z, v.w};
#pragma unroll
  for (int q = 0; q < 4; ++q) {
    _Float16 hh = (_Float16)vs[q];
    _Float16 ll = (_Float16)(vs[q] - (float)hh);
    hv[q] = hh; lv[q] = ll;
  }
  ((f16x4*)h)[i] = hv;
  ((f16x4*)l)[i] = lv;
}

// ---------------- 2-term fp16 MFMA GEMM, 256x256 tile, phased schedule ----------------
// out[m][j] = sum_k A[m][k] * (Bh[j][k] + Bl[j][k])
// 8 waves (2M x 4N), per-wave 128x64 output, K-tile = 32, 3-deep LDS buffers
// (144 KiB), global_load_lds prefetch with counted vmcnt(6) (never 0 in main
// loop), per-phase barriers + setprio(1) around MFMA clusters (T3+T4+T5),
// bijective XCD-aware block swizzle (T1).  LDS in fragment order -> 0 bank
// conflicts, and global_load_lds dest stays linear (rule #21).
// EPI 0: qkv epilogue (bias + phi/mask -> [B,H,N,D] fp32); EPI 1: bias + row-major fp32.
template <int EPI>
__global__ __launch_bounds__(512, 2) void gemm256_k(
    const _Float16* __restrict__ A,
    const _Float16* __restrict__ Bh, const _Float16* __restrict__ Bl,
    const float* __restrict__ bias, const float* __restrict__ valid,
    float* __restrict__ qf, float* __restrict__ kf, float* __restrict__ vv,
    float* __restrict__ outp, int jb, int jshift) {
  // per K-tile buffer: A 256x32 (8192 halfs) + Bh 8192 + Bl 8192 = 48 KiB; x3 = 144 KiB
  __shared__ _Float16 lds[73728];
  const int tid = threadIdx.x;
  const int lane = tid & 63, w = tid >> 6;
  const int lm = lane & 15, lq = lane >> 4;
  const int wm = w >> 2, wj = w & 3;

  // XCD swizzle: consecutive bids round-robin XCDs; give each XCD a contiguous
  // chunk of work ids.  nwg is always a multiple of 8 here (512/256/256).
  const int nwg = gridDim.x;
  const int q8 = nwg >> 3;
  const int wid = (blockIdx.x & 7) * q8 + (blockIdx.x >> 3);
  const int j_blk = wid & ((1 << jshift) - 1);
  const int m_blk = wid >> jshift;
  const int m0 = m_blk * 256;
  const int jg0 = jb + j_blk * 256;

  // per-lane global source offsets (halfs); frag f = r*8 + w covers rows f*16+lm
  const size_t gA0 = (size_t)(m0 + w * 16 + lm) * GK + lq * 8;
  const size_t gA1 = gA0 + (size_t)128 * GK;
  const size_t gB0 = (size_t)(jg0 + w * 16 + lm) * GK + lq * 8;
  const size_t gB1 = gB0 + (size_t)128 * GK;

  // ---- prologue: stage tiles 0 (buf0) and 1 (buf1), wait tile0 only ----
#pragma unroll
  for (int tt = 0; tt < 2; ++tt) {
    _Float16* sq = lds + tt * 24576;
    const size_t ks = (size_t)tt * 32;
    GLOAD(A + gA0 + ks, sq + w * 512);
    GLOAD(A + gA1 + ks, sq + 4096 + w * 512);
    GLOAD(Bh + gB0 + ks, sq + 8192 + w * 512);
    GLOAD(Bh + gB1 + ks, sq + 12288 + w * 512);
    GLOAD(Bl + gB0 + ks, sq + 16384 + w * 512);
    GLOAD(Bl + gB1 + ks, sq + 20480 + w * 512);
  }
  WAITV6();
  BAR();

  f32x4 acc[8][4] = {};
  int pc = 0, ps = 2;
  for (int t = 0; t < 32; ++t) {
    const _Float16* bb = lds + pc * 24576;
    _Float16* sq = lds + ps * 24576;
    const bool st = (t + 2 < 32);
    const size_t ks = (size_t)(t + 2) * 32;
    f16x8 a0[4], a1[4], bh[4], bl[4];

    // ---- phase 1: read a0 + bh; issue A prefetch; MFMA a0*bh ----
#pragma unroll
    for (int i = 0; i < 4; ++i)
      a0[i] = *(const f16x8*)&bb[(wm * 8 + i) * 512 + lane * 8];
#pragma unroll
    for (int j = 0; j < 4; ++j)
      bh[j] = *(const f16x8*)&bb[8192 + (wj * 4 + j) * 512 + lane * 8];
    if (st) {
      GLOAD(A + gA0 + ks, sq + w * 512);
      GLOAD(A + gA1 + ks, sq + 4096 + w * 512);
    }
    BAR(); WAITL0();
    PRIO1();
#pragma unroll
    for (int i = 0; i < 4; ++i)
#pragma unroll
      for (int j = 0; j < 4; ++j)
        acc[i][j] = mfma16h(a0[i], bh[j], acc[i][j]);
    PRIO0(); BAR();

    // ---- phase 2: read a1; issue Bh prefetch; MFMA a1*bh ----
#pragma unroll
    for (int i = 0; i < 4; ++i)
      a1[i] = *(const f16x8*)&bb[(wm * 8 + 4 + i) * 512 + lane * 8];
    if (st) {
      GLOAD(Bh + gB0 + ks, sq + 8192 + w * 512);
      GLOAD(Bh + gB1 + ks, sq + 12288 + w * 512);
    }
    BAR(); WAITL0();
    PRIO1();
#pragma unroll
    for (int i = 0; i < 4; ++i)
#pragma unroll
      for (int j = 0; j < 4; ++j)
        acc[4 + i][j] = mfma16h(a1[i], bh[j], acc[4 + i][j]);
    PRIO0(); BAR();

    // ---- phase 3: read bl; issue Bl prefetch; MFMA a0*bl ----
#pragma unroll
    for (int j = 0; j < 4; ++j)
      bl[j] = *(const f16x8*)&bb[16384 + (wj * 4 + j) * 512 + lane * 8];
    if (st) {
      GLOAD(Bl + gB0 + ks, sq + 16384 + w * 512);
      GLOAD(Bl + gB1 + ks, sq + 20480 + w * 512);
    }
    BAR(); WAITL0();
    PRIO1();
#pragma unroll
    for (int i = 0; i < 4; ++i)
#pragma unroll
      for (int j = 0; j < 4; ++j)
        acc[i][j] = mfma16h(a0[i], bl[j], acc[i][j]);
    PRIO0(); BAR();

    // ---- phase 4: MFMA a1*bl; counted end-of-tile wait (tile t+1 ready) ----
    PRIO1();
#pragma unroll
    for (int i = 0; i < 4; ++i)
#pragma unroll
      for (int j = 0; j < 4; ++j)
        acc[4 + i][j] = mfma16h(a1[i], bl[j], acc[4 + i][j]);
    PRIO0();
    if (t < 30)       { WAITV6(); }
    else if (t == 30) { WAITV0(); }
    if (t < 31) BAR();
    pc = (pc == 2) ? 0 : pc + 1;
    ps = (ps == 2) ? 0 : ps + 1;
  }

  // C/D layout: col = lane&15, row = (lane>>4)*4 + reg   [m89-verified]
  if (EPI == 0) {
    const int ty = jg0 >> 10;  // 0:q 1:k 2:v  (uniform per block: 256 | 1024)
    float* dst = (ty == 0) ? qf : ((ty == 1) ? kf : vv);
    float vld[8][4];
#pragma unroll
    for (int i = 0; i < 8; ++i)
#pragma unroll
      for (int r = 0; r < 4; ++r)
        vld[i][r] = (ty == 0) ? 1.0f : valid[m0 + wm * 128 + i * 16 + lq * 4 + r];
#pragma unroll
    for (int jt = 0; jt < 4; ++jt) {
      int jcol = jg0 + wj * 64 + jt * 16 + lm;
      float bj = bias[jcol];
      int c = jcol & 1023, hd = c >> 6, d = c & 63;
#pragma unroll
      for (int i = 0; i < 8; ++i)
#pragma unroll
        for (int r = 0; r < 4; ++r) {
          int m = m0 + wm * 128 + i * 16 + lq * 4 + r;
          int b = m >> 12, n = m & 4095;
          float val = acc[i][jt][r] + bj;
          if (ty <= 1) val = phi_f(val);
          if (ty >= 1) val *= vld[i][r];
          dst[(((size_t)(b * H_ + hd) * N_ + n) << 6) + d] = val;
        }
    }
  } else {
#pragma unroll
    for (int jt = 0; jt < 4; ++jt) {
      int jcol = jg0 + wj * 64 + jt * 16 + lm;
      float bj = bias[jcol];
#pragma unroll
      for (int i = 0; i < 8; ++i)
#pragma unroll
        for (int r = 0; r < 4; ++r) {
          int m = m0 + wm * 128 + i * 16 + lq * 4 + r;
          outp[(size_t)m * C_ + jcol] = acc[i][jt][r] + bj;
        }
    }
  }
}

// ---------------- kv partials: kv[bh][d][e] = sum_n kf[bh][n][d]*v[bh][n][e]; z[bh][d] ----------------
__global__ __launch_bounds__(256) void kv_partial_k(
    const float* __restrict__ kf, const float* __restrict__ vv,
    float* __restrict__ kvp, float* __restrict__ zp) {
  const int bh = blockIdx.x, ch = blockIdx.y;
  const float* kfr = kf + ((size_t)bh * N_ + ch * CHROWS) * 64;
  const float* vr  = vv + ((size_t)bh * N_ + ch * CHROWS) * 64;
  __shared__ float ks[8][64], vs[8][64];
  const int tid = threadIdx.x;
  const int d0 = tid >> 2, eg = tid & 3;
  float acc[16] = {};
  float zacc = 0.f;
  for (int nb = 0; nb < CHROWS; nb += 8) {
    {
      int which = tid >> 7;
      int fl = tid & 127;
      int rr = fl >> 4, cc = (fl & 15) * 4;
      const float* src = which ? vr : kfr;
      float4 t4 = *(const float4*)&src[(size_t)(nb + rr) * 64 + cc];
      float* d = which ? &vs[rr][cc] : &ks[rr][cc];
      *(float4*)d = t4;
    }
    __syncthreads();
#pragma unroll
    for (int r = 0; r < 8; ++r) {
      float kd = ks[r][d0];
      if (eg == 0) zacc += kd;
#pragma unroll
      for (int i = 0; i < 16; ++i) acc[i] += kd * vs[r][eg * 16 + i];
    }
    __syncthreads();
  }
  size_t base = ((size_t)bh * NCH + ch) * 4096 + (size_t)d0 * 64 + eg * 16;
#pragma unroll
  for (int i = 0; i < 16; i += 4)
    *(float4*)&kvp[base + i] = make_float4(acc[i], acc[i+1], acc[i+2], acc[i+3]);
  if (eg == 0) zp[((size_t)bh * NCH + ch) * 64 + d0] = zacc;
}

__global__ __launch_bounds__(256) void kv_reduce_k(
    const float* __restrict__ kvp, const float* __restrict__ zp,
    float* __restrict__ kv, float* __restrict__ z) {
  const int bh = blockIdx.x, tid = threadIdx.x;
  for (int i = tid; i < 4096; i += 256) {
    float s = 0.f;
#pragma unroll
    for (int c = 0; c < NCH; ++c) s += kvp[((size_t)bh * NCH + c) * 4096 + i];
    kv[(size_t)bh * 4096 + i] = s;
  }
  if (tid < 64) {
    float s = 0.f;
#pragma unroll
    for (int c = 0; c < NCH; ++c) s += zp[((size_t)bh * NCH + c) * 64 + tid];
    z[bh * 64 + tid] = s;
  }
}

// ---------------- apply: Y[b,n,h*64+e] = (qf . kv) / max(qf . z, eps), fp16 out ----------------
__global__ __launch_bounds__(256) void attn_apply_k(
    const float* __restrict__ qf, const float* __restrict__ kv,
    const float* __restrict__ z, _Float16* __restrict__ Y) {
  const int bh = blockIdx.x, nt = blockIdx.y;
  const int b = bh >> 4, hd = bh & 15;
  __shared__ float qs[128][65];
  __shared__ float kvs[64][68];
  __shared__ float zs[64];
  __shared__ float dens[128];
  const int tid = threadIdx.x;
  const float* qrow = qf + ((size_t)bh * N_ + nt * 128) * 64;
#pragma unroll
  for (int i = 0; i < 4; ++i) {
    int fl = tid + i * 256;
    int d = fl >> 4, cc = (fl & 15) * 4;
    float4 t4 = *(const float4*)&kv[(size_t)bh * 4096 + d * 64 + cc];
    kvs[d][cc] = t4.x; kvs[d][cc+1] = t4.y; kvs[d][cc+2] = t4.z; kvs[d][cc+3] = t4.w;
  }
  if (tid < 64) zs[tid] = z[bh * 64 + tid];
#pragma unroll
  for (int i = 0; i < 8; ++i) {
    int fl = tid + i * 256;
    int r = fl >> 4, cc = (fl & 15) * 4;
    float4 t4 = *(const float4*)&qrow[(size_t)r * 64 + cc];
    qs[r][cc] = t4.x; qs[r][cc+1] = t4.y; qs[r][cc+2] = t4.z; qs[r][cc+3] = t4.w;
  }
  __syncthreads();
  {
    int n = tid >> 1, half = tid & 1;
    float s = 0.f;
#pragma unroll
    for (int dd = 0; dd < 32; ++dd) {
      int d = half * 32 + dd;
      s += qs[n][d] * zs[d];
    }
    float other = __shfl_down(s, 1);
    if (half == 0) dens[n] = fmaxf(s + other, 1e-6f);
  }
  __syncthreads();
  const int ng = tid >> 3, eg = tid & 7;
  float acc[4][8] = {};
  for (int d = 0; d < 64; ++d) {
    float kvrow[8];
    *(float4*)&kvrow[0] = *(const float4*)&kvs[d][eg * 8];
    *(float4*)&kvrow[4] = *(const float4*)&kvs[d][eg * 8 + 4];
#pragma unroll
    for (int i = 0; i < 4; ++i) {
      float a = qs[ng * 4 + i][d];
#pragma unroll
      for (int j = 0; j < 8; ++j) acc[i][j] += a * kvrow[j];
    }
  }
#pragma unroll
  for (int i = 0; i < 4; ++i) {
    int nl = ng * 4 + i;
    int n = nt * 128 + nl;
    float inv = 1.0f / dens[nl];
    size_t off = ((size_t)b * N_ + n) * C_ + hd * 64 + eg * 8;
    f16x8 hv;
#pragma unroll
    for (int j = 0; j < 8; ++j) hv[j] = (_Float16)(acc[i][j] * inv);
    *(f16x8*)&Y[off] = hv;
  }
}

extern "C" void kernel_launch(void* const* d_in, const int* in_sizes, int n_in,
                              void* d_out, int out_size, void* d_ws, size_t ws_size,
                              hipStream_t stream) {
  const float* x      = (const float*)d_in[0];
  const float* W_qkv  = (const float*)d_in[1];
  const float* b_qkv  = (const float*)d_in[2];
  const float* W_out  = (const float*)d_in[3];
  const float* b_out  = (const float*)d_in[4];
  const void*  mask   = d_in[5];
  float* out = (float*)d_out;

  const size_t bhnd = (size_t)B_ * H_ * N_ * D_;   // 16,777,216
  float* ws = (float*)d_ws;
  float* buf1 = ws;                    // kf, then qf (fp32)
  float* buf2 = ws + bhnd;             // v (fp32), then Y (fp16)
  _Float16* Xh  = (_Float16*)(ws + 2 * bhnd);      // bhnd halfs
  _Float16* Wqh = Xh + bhnd;                       // 3072*1024
  _Float16* Wql = Wqh + (size_t)3072 * 1024;
  _Float16* Woh = Wql + (size_t)3072 * 1024;       // 1024*1024
  _Float16* Wol = Woh + (size_t)1024 * 1024;
  float* tail2 = (float*)(Wol + (size_t)1024 * 1024);
  float* kvp = tail2;                              // 64*8*4096
  float* zp  = kvp + (size_t)64 * NCH * 4096;
  float* kv  = zp + (size_t)64 * NCH * 64;
  float* z   = kv + (size_t)64 * 4096;
  float* valid = z + 64 * 64;
  int*   flag  = (int*)(valid + M_);

  _Float16* Y = (_Float16*)buf2;

  mask_detect_k<<<1, 256, 0, stream>>>((const unsigned int*)mask, flag);
  mask_convert_k<<<M_ / 256, 256, 0, stream>>>(mask, flag, valid);
  conv_f16_k<<<(int)(bhnd / 4 / 256), 256, 0, stream>>>(x, Xh, (int)(bhnd / 4));
  split_f16_k<<<3072 * 1024 / 4 / 256, 256, 0, stream>>>(W_qkv, Wqh, Wql, 3072 * 1024 / 4);
  split_f16_k<<<1024 * 1024 / 4 / 256, 256, 0, stream>>>(W_out, Woh, Wol, 1024 * 1024 / 4);
  // phase A: K and V projections (j in [1024,3072)) -> kf(buf1), v(buf2)
  // grid = 64 m-blocks x 8 j-blocks = 512 (1D, swizzled in-kernel)
  gemm256_k<0><<<512, 512, 0, stream>>>(
      Xh, Wqh, Wql, b_qkv, valid, buf1, buf1, buf2, nullptr, 1024, 3);
  kv_partial_k<<<dim3(B_ * H_, NCH), 256, 0, stream>>>(buf1, buf2, kvp, zp);
  kv_reduce_k<<<B_ * H_, 256, 0, stream>>>(kvp, zp, kv, z);
  // phase B: Q projection (j in [0,1024)) -> qf into buf1 (kf dead)
  gemm256_k<0><<<256, 512, 0, stream>>>(
      Xh, Wqh, Wql, b_qkv, valid, buf1, buf1, buf2, nullptr, 0, 2);
  // apply: reads qf(buf1), writes Y (fp16) into buf2 (v dead)
  attn_apply_k<<<dim3(B_ * H_, N_ / 128), 256, 0, stream>>>(buf1, kv, z, Y);
  // out-proj: A = Y (fp16 single), B = W_out split-2
  gemm256_k<1><<<256, 512, 0, stream>>>(
      Y, Woh, Wol, b_out, valid, nullptr, nullptr, nullptr, out, 0, 2);
}